// Round 6
// baseline (455.264 us; speedup 1.0000x reference)
//
#include <hip/hip_runtime.h>
#include <math.h>

typedef short s16x8 __attribute__((ext_vector_type(8)));
typedef short s16x4 __attribute__((ext_vector_type(4)));
typedef float f32x4 __attribute__((ext_vector_type(4)));

// ws float-offsets
#define W1PK_OFF   0           // 128 x {w1c0,w1c1,w1c2,b1} = 512 floats
#define B2PK_OFF   512        // 112 floats (zero-padded)
#define B3PK_OFF   624        // 80 floats
#define WSHORT_OFF 704        // short region (16B aligned)
// short-offsets inside short region (frag-ordered, per (n,ks): 512 shorts)
#define W2H_S 0                // 7*4*512 = 14336
#define W2L_S 14336
#define W3H_S 28672            // 5*4*512 = 10240
#define W3L_S 38912

__device__ __forceinline__ void bsplit(float x, short& hi, short& lo) {
    unsigned u  = __float_as_uint(x);
    unsigned uh = u & 0xFFFF0000u;
    hi = (short)(uh >> 16);
    float r = x - __uint_as_float(uh);
    lo = (short)(__float_as_uint(r) >> 16);
}

// Prep: pack w1/b1 rows, pad biases, frag-ordered split weights.
// Frag (n,ks): lane=ln+16*l4 holds w[16n+ln][ks*32+l4*8+j], j=0..7.
__global__ void ds_prep(const float* __restrict__ pw1, const float* __restrict__ pb1,
                        const float* __restrict__ pw2, const float* __restrict__ pb2,
                        const float* __restrict__ pw3, const float* __restrict__ pb3,
                        float* __restrict__ wsF, short* __restrict__ wsS) {
    int t = blockIdx.x * 256 + threadIdx.x;
    if (t < 128) {
        f32x4 v = 0.f;
        if (t < 120) { v.x = pw1[t*3]; v.y = pw1[t*3+1]; v.z = pw1[t*3+2]; v.w = pb1[t]; }
        *(f32x4*)(wsF + W1PK_OFF + t * 4) = v; return;
    }
    t -= 128;
    if (t < 112) { wsF[B2PK_OFF + t] = (t < 100) ? pb2[t] : 0.f; return; }
    t -= 112;
    if (t < 80)  { wsF[B3PK_OFF + t] = pb3[t]; return; }
    t -= 80;
    if (t < 14336) {
        int j = t & 7, lane = (t >> 3) & 63, c = t >> 9;
        int ks = c & 3, n = c >> 2;
        int ln = lane & 15, l4 = lane >> 4;
        int row = 16 * n + ln, col = ks * 32 + l4 * 8 + j;
        float v = (row < 100 && col < 120) ? pw2[row * 120 + col] : 0.f;
        short hi, lo; bsplit(v, hi, lo);
        wsS[W2H_S + t] = hi; wsS[W2L_S + t] = lo; return;
    }
    t -= 14336;
    if (t < 10240) {
        int j = t & 7, lane = (t >> 3) & 63, c = t >> 9;
        int ks = c & 3, n = c >> 2;
        int ln = lane & 15, l4 = lane >> 4;
        int row = 16 * n + ln, col = ks * 32 + l4 * 8 + j;
        float v = (col < 100) ? pw3[row * 100 + col] : 0.f;
        short hi, lo; bsplit(v, hi, lo);
        wsS[W3H_S + t] = hi; wsS[W3L_S + t] = lo; return;
    }
}

#define MFMA_B16(A, B, C) __builtin_amdgcn_mfma_f32_16x16x32_bf16((A), (B), (C), 0, 0, 0)

// one K-slice of an L2 o-tile: h1 frags re-read from LDS, weights from global
#define L2KS(N2, KS) do {                                                       \
    const s16x8 bhk = *(const s16x8*)(h1H + h1base + (((KS) ^ kperm) << 3));    \
    const s16x8 blk = *(const s16x8*)(h1L + h1base + (((KS) ^ kperm) << 3));    \
    const s16x8 ah  = *(const s16x8*)(w2h + (((N2) * 4 + (KS)) * 64 + l) * 8);  \
    const s16x8 al  = *(const s16x8*)(w2l + (((N2) * 4 + (KS)) * 64 + l) * 8);  \
    a2h = MFMA_B16(ah, bhk, a2h);                                               \
    a2x = MFMA_B16(ah, blk, a2x);                                               \
    a2x = MFMA_B16(al, bhk, a2x);                                               \
} while (0)

// full L2 o-tile N2 -> bias+relu+split into HH/HL (s16x4)
#define L2TILE(N2, HH, HL) do {                                                 \
    f32x4 a2h = 0.f, a2x = 0.f;                                                 \
    L2KS(N2, 0); L2KS(N2, 1); L2KS(N2, 2); L2KS(N2, 3);                         \
    const int o0 = 16 * (N2) + 4 * l4;                                          \
    f32x4 bb = *(const f32x4*)(sb2 + o0);                                       \
    _Pragma("unroll")                                                           \
    for (int r = 0; r < 4; ++r) {                                               \
        float v = fmaxf(a2h[r] + a2x[r] + bb[r], 0.f);                          \
        short hi, lo; bsplit(v, hi, lo);                                        \
        HH[r] = hi; HL[r] = lo;                                                 \
    }                                                                           \
    __builtin_amdgcn_sched_barrier(0);                                          \
} while (0)

#define L3KS(N3, KS3, ACC) do {                                                 \
    const s16x8 a3h = *(const s16x8*)(w3h + (((N3) * 4 + (KS3)) * 64 + l) * 8); \
    const s16x8 a3l = *(const s16x8*)(w3l + (((N3) * 4 + (KS3)) * 64 + l) * 8); \
    ACC = MFMA_B16(a3h, b3h, ACC);                                              \
    ACC = MFMA_B16(a3h, b3l, ACC);                                              \
    ACC = MFMA_B16(a3l, b3h, ACC);                                              \
} while (0)

// one h2 k-slice: two L2 o-tiles -> per-wave LDS bounce -> 5 L3 tiles fed
#define KS3_STEP(KS3, N2A, N2B) do {                                            \
    s16x4 hh0 = 0, hl0 = 0, hh1 = 0, hl1 = 0;                                   \
    L2TILE(N2A, hh0, hl0);                                                      \
    if ((N2B) < 7) { L2TILE(N2B, hh1, hl1); }                                   \
    *(s16x4*)(bnH + bnBase + ln * 32 + l4 * 4)      = hh0;                      \
    *(s16x4*)(bnL + bnBase + ln * 32 + l4 * 4)      = hl0;                      \
    *(s16x4*)(bnH + bnBase + ln * 32 + 16 + l4 * 4) = hh1;                      \
    *(s16x4*)(bnL + bnBase + ln * 32 + 16 + l4 * 4) = hl1;                      \
    const s16x8 b3h = *(const s16x8*)(bnH + bnBase + ln * 32 + klo);            \
    const s16x8 b3l = *(const s16x8*)(bnL + bnBase + ln * 32 + klo);            \
    L3KS(0, KS3, acc3_0);                                                       \
    L3KS(1, KS3, acc3_1);                                                       \
    L3KS(2, KS3, acc3_2);                                                       \
    L3KS(3, KS3, acc3_3);                                                       \
    L3KS(4, KS3, acc3_4);                                                       \
    __builtin_amdgcn_sched_barrier(0);                                          \
} while (0)

#define POOLN(N3, ACC) do {                                                     \
    const int o0 = 16 * (N3) + 4 * l4;                                          \
    f32x4 bb = *(const f32x4*)(sb3 + o0);                                       \
    _Pragma("unroll")                                                           \
    for (int r = 0; r < 4; ++r) {                                               \
        float v = fmaxf(ACC[r] + bb[r], 0.f);                                   \
        v += __shfl_xor(v, 1);                                                  \
        v += __shfl_xor(v, 2);                                                  \
        v += __shfl_xor(v, 4);                                                  \
        v += __shfl_xor(v, 8);                                                  \
        if (ln == 0) pbuf[o0 + r] = v;                                          \
    }                                                                           \
} while (0)

// Fully fused: 512 blocks x 512 thr; 4 batches/block; wave w owns el-tile w.
// h1 frags in LDS (not regs), sched_barriers bound load hoisting -> no spills.
__global__ __launch_bounds__(512)
__attribute__((amdgpu_waves_per_eu(2)))
void ds_phi(const float* __restrict__ dyn, const float* __restrict__ stat,
            const float* __restrict__ wsF, const short* __restrict__ wsS,
            const float* __restrict__ rw1, const float* __restrict__ rb1,
            const float* __restrict__ rw2, const float* __restrict__ rb2,
            const float* __restrict__ rw3, const float* __restrict__ rb3,
            const float* __restrict__ qw1, const float* __restrict__ qb1,
            const float* __restrict__ qw2, const float* __restrict__ qb2,
            const float* __restrict__ qw3, const float* __restrict__ qb3,
            float* __restrict__ out) {
    const int tid = threadIdx.x;
    const int w = tid >> 6, l = tid & 63, ln = l & 15, l4 = l >> 4;
    const int klo = l4 * 8;
    const int kperm = (l >> 1) & 3;
    const int h1base = tid * 32;

    __shared__ short h1H[16384], h1L[16384];   // per-thread 32+32 shorts
    __shared__ short bnH[4096], bnL[4096];     // per-wave 512-short bounce
    __shared__ float sw1[512], sb2[112], sb3[80];
    __shared__ float poolbuf[8 * 80];
    __shared__ __align__(16) float pooledS[80];
    __shared__ __align__(16) float r1s[64], r2s[64], xcat[48], q1s[200], q2s[104];
    __shared__ float logits[3];

    if (tid < 128) *(f32x4*)(sw1 + tid * 4) = *(const f32x4*)(wsF + W1PK_OFF + tid * 4);
    if (tid < 112) sb2[tid] = wsF[B2PK_OFF + tid];
    if (tid < 80)  sb3[tid] = wsF[B3PK_OFF + tid];
    __syncthreads();

    const short* w2h = wsS + W2H_S;
    const short* w2l = wsS + W2L_S;
    const short* w3h = wsS + W3H_S;
    const short* w3l = wsS + W3L_S;
    const int el = 16 * w + ln;
    const int bnBase = w << 9;
    float* pbuf = poolbuf + w * 80;

    #pragma unroll 1
    for (int g = 0; g < 4; ++g) {
        const int b = blockIdx.x * 4 + g;
        const float* xp = dyn + (size_t)b * 384 + el * 3;
        const float x0 = xp[0], x1 = xp[1], x2 = xp[2];

        // h1 frags -> LDS (k>=120 rows zero via sw1 padding)
        #define H1GEN(KS) do {                                                  \
            s16x8 vh, vl;                                                       \
            _Pragma("unroll")                                                   \
            for (int j = 0; j < 8; ++j) {                                       \
                const int k = (KS) * 32 + klo + j;                              \
                f32x4 c = *(const f32x4*)(sw1 + 4 * k);                         \
                float v = fmaf(x0, c.x, fmaf(x1, c.y, fmaf(x2, c.z, c.w)));     \
                v = fmaxf(v, 0.f);                                              \
                short hi, lo; bsplit(v, hi, lo);                                \
                vh[j] = hi; vl[j] = lo;                                         \
            }                                                                   \
            *(s16x8*)(h1H + h1base + (((KS) ^ kperm) << 3)) = vh;               \
            *(s16x8*)(h1L + h1base + (((KS) ^ kperm) << 3)) = vl;               \
        } while (0)
        H1GEN(0); H1GEN(1); H1GEN(2); H1GEN(3);
        #undef H1GEN
        __builtin_amdgcn_sched_barrier(0);

        f32x4 acc3_0 = 0.f, acc3_1 = 0.f, acc3_2 = 0.f, acc3_3 = 0.f, acc3_4 = 0.f;

        KS3_STEP(0, 0, 1);
        KS3_STEP(1, 2, 3);
        KS3_STEP(2, 4, 5);
        KS3_STEP(3, 6, 7);   // n2=7 stays zero

        POOLN(0, acc3_0);
        POOLN(1, acc3_1);
        POOLN(2, acc3_2);
        POOLN(3, acc3_3);
        POOLN(4, acc3_4);
        __syncthreads();
        if (tid < 80) {
            float s = 0.f;
            #pragma unroll
            for (int ww = 0; ww < 8; ++ww) s += poolbuf[ww * 80 + tid];
            pooledS[tid] = s;
        }
        __syncthreads();

        // ---- fused tail (rho + q + softmax), pooled in LDS ----
        if (tid < 60) {
            float a = rb1[tid];
            for (int k = 0; k < 80; k += 4) {
                f32x4 pv = *(const f32x4*)(pooledS + k);
                f32x4 wv = *(const f32x4*)(rw1 + tid * 80 + k);
                a += pv.x * wv.x + pv.y * wv.y + pv.z * wv.z + pv.w * wv.w;
            }
            r1s[tid] = fmaxf(a, 0.0f);
        }
        __syncthreads();
        if (tid < 60) {
            float a = rb2[tid];
            for (int k = 0; k < 60; k += 4) {
                f32x4 pv = *(const f32x4*)(r1s + k);
                f32x4 wv = *(const f32x4*)(rw2 + tid * 60 + k);
                a += pv.x * wv.x + pv.y * wv.y + pv.z * wv.z + pv.w * wv.w;
            }
            r2s[tid] = fmaxf(a, 0.0f);
        }
        __syncthreads();
        if (tid < 40) {
            float a = rb3[tid];
            for (int k = 0; k < 60; k += 4) {
                f32x4 pv = *(const f32x4*)(r2s + k);
                f32x4 wv = *(const f32x4*)(rw3 + tid * 60 + k);
                a += pv.x * wv.x + pv.y * wv.y + pv.z * wv.z + pv.w * wv.w;
            }
            xcat[tid] = a;
        }
        if (tid >= 40 && tid < 43) xcat[tid] = stat[(size_t)b * 3 + (tid - 40)];
        __syncthreads();
        if (tid < 200) {
            float a = qb1[tid];
            const float* wv = qw1 + tid * 43;
            for (int k = 0; k < 43; ++k) a += xcat[k] * wv[k];
            q1s[tid] = fmaxf(a, 0.0f);
        }
        __syncthreads();
        if (tid < 100) {
            float a = qb2[tid];
            for (int k = 0; k < 200; k += 4) {
                f32x4 pv = *(const f32x4*)(q1s + k);
                f32x4 wv = *(const f32x4*)(qw2 + tid * 200 + k);
                a += pv.x * wv.x + pv.y * wv.y + pv.z * wv.z + pv.w * wv.w;
            }
            q2s[tid] = fmaxf(a, 0.0f);
        }
        __syncthreads();
        if (tid < 96) {
            int o = tid >> 5, l2 = tid & 31;
            float a = 0.0f;
            for (int k = l2; k < 100; k += 32) a += q2s[k] * qw3[o * 100 + k];
            #pragma unroll
            for (int d = 16; d > 0; d >>= 1) a += __shfl_down(a, d, 32);
            if (l2 == 0) logits[o] = a + qb3[o];
        }
        __syncthreads();
        if (tid < 3) {
            float l0 = logits[0], l1 = logits[1], l2v = logits[2];
            float m  = fmaxf(l0, fmaxf(l1, l2v));
            float e0 = __expf(l0 - m), e1 = __expf(l1 - m), e2 = __expf(l2v - m);
            float inv = 1.0f / (e0 + e1 + e2);
            float mine = (tid == 0) ? e0 : ((tid == 1) ? e1 : e2);
            out[(size_t)b * 3 + tid] = mine * inv;
        }
        __syncthreads();
    }
}

extern "C" void kernel_launch(void* const* d_in, const int* in_sizes, int n_in,
                              void* d_out, int out_size, void* d_ws, size_t ws_size,
                              hipStream_t stream) {
    const float* dyn  = (const float*)d_in[0];
    const float* stat = (const float*)d_in[1];
    const float* pw1  = (const float*)d_in[2];
    const float* pb1  = (const float*)d_in[3];
    const float* pw2  = (const float*)d_in[4];
    const float* pb2  = (const float*)d_in[5];
    const float* pw3  = (const float*)d_in[6];
    const float* pb3  = (const float*)d_in[7];
    const float* rw1  = (const float*)d_in[8];
    const float* rb1  = (const float*)d_in[9];
    const float* rw2  = (const float*)d_in[10];
    const float* rb2  = (const float*)d_in[11];
    const float* rw3  = (const float*)d_in[12];
    const float* rb3  = (const float*)d_in[13];
    const float* qw1  = (const float*)d_in[14];
    const float* qb1  = (const float*)d_in[15];
    const float* qw2  = (const float*)d_in[16];
    const float* qb2  = (const float*)d_in[17];
    const float* qw3  = (const float*)d_in[18];
    const float* qb3  = (const float*)d_in[19];
    float* out = (float*)d_out;

    float* wsF = (float*)d_ws;
    short* wsS = (short*)(wsF + WSHORT_OFF);
    const int B = in_sizes[0] / 384;   // 2048

    ds_prep<<<dim3(98), dim3(256), 0, stream>>>(pw1, pb1, pw2, pb2, pw3, pb3, wsF, wsS);
    ds_phi<<<dim3(B / 4), dim3(512), 0, stream>>>(dyn, stat, wsF, wsS,
        rw1, rb1, rw2, rb2, rw3, rb3,
        qw1, qb1, qw2, qb2, qw3, qb3, out);
}

// Round 8
// 190.370 us; speedup vs baseline: 2.3915x; 2.3915x over previous
//
#include <hip/hip_runtime.h>
#include <math.h>

typedef short s16x8 __attribute__((ext_vector_type(8)));
typedef short s16x4 __attribute__((ext_vector_type(4)));
typedef float f32x4 __attribute__((ext_vector_type(4)));

// ws float-offsets
#define W1PK_OFF   0           // 128 x {w1c0,w1c1,w1c2,b1} = 512 floats
#define B2PK_OFF   512         // 112 floats (zero-padded)
#define B3PK_OFF   624         // 80 floats
#define WSHORT_OFF 704         // short region (16B aligned)
// short-offsets inside short region (frag-ordered, per (n,ks): 512 shorts)
#define W2H_S 0                // 7*4*512 = 14336
#define W2L_S 14336
#define W3H_S 28672            // 5*4*512 = 10240
#define W3L_S 38912

__device__ __forceinline__ void bsplit(float x, short& hi, short& lo) {
    unsigned u  = __float_as_uint(x);
    unsigned uh = u & 0xFFFF0000u;
    hi = (short)(uh >> 16);
    float r = x - __uint_as_float(uh);
    lo = (short)(__float_as_uint(r) >> 16);
}

// Prep: pack w1/b1 rows, pad biases, frag-ordered split weights.
// Frag (n,ks): lane=ln+16*l4 holds w[16n+ln][ks*32+l4*8+j], j=0..7.
__global__ void ds_prep(const float* __restrict__ pw1, const float* __restrict__ pb1,
                        const float* __restrict__ pw2, const float* __restrict__ pb2,
                        const float* __restrict__ pw3, const float* __restrict__ pb3,
                        float* __restrict__ wsF, short* __restrict__ wsS) {
    int t = blockIdx.x * 256 + threadIdx.x;
    if (t < 128) {
        f32x4 v = 0.f;
        if (t < 120) { v.x = pw1[t*3]; v.y = pw1[t*3+1]; v.z = pw1[t*3+2]; v.w = pb1[t]; }
        *(f32x4*)(wsF + W1PK_OFF + t * 4) = v; return;
    }
    t -= 128;
    if (t < 112) { wsF[B2PK_OFF + t] = (t < 100) ? pb2[t] : 0.f; return; }
    t -= 112;
    if (t < 80)  { wsF[B3PK_OFF + t] = pb3[t]; return; }
    t -= 80;
    if (t < 14336) {
        int j = t & 7, lane = (t >> 3) & 63, c = t >> 9;
        int ks = c & 3, n = c >> 2;
        int ln = lane & 15, l4 = lane >> 4;
        int row = 16 * n + ln, col = ks * 32 + l4 * 8 + j;
        float v = (row < 100 && col < 120) ? pw2[row * 120 + col] : 0.f;
        short hi, lo; bsplit(v, hi, lo);
        wsS[W2H_S + t] = hi; wsS[W2L_S + t] = lo; return;
    }
    t -= 14336;
    if (t < 10240) {
        int j = t & 7, lane = (t >> 3) & 63, c = t >> 9;
        int ks = c & 3, n = c >> 2;
        int ln = lane & 15, l4 = lane >> 4;
        int row = 16 * n + ln, col = ks * 32 + l4 * 8 + j;
        float v = (col < 100) ? pw3[row * 100 + col] : 0.f;
        short hi, lo; bsplit(v, hi, lo);
        wsS[W3H_S + t] = hi; wsS[W3L_S + t] = lo; return;
    }
}

#define MFMA_B16(A, B, C) __builtin_amdgcn_mfma_f32_16x16x32_bf16((A), (B), (C), 0, 0, 0)

// one K-slice of an L2 o-tile: weights from global (L2-hot), h1 frags in regs
#define L2KS(N2, KS, BH, BL) do {                                               \
    const s16x8 ah = *(const s16x8*)(w2h + (((N2) * 4 + (KS)) * 64 + l) * 8);   \
    const s16x8 al = *(const s16x8*)(w2l + (((N2) * 4 + (KS)) * 64 + l) * 8);   \
    a2h = MFMA_B16(ah, BH, a2h);                                                \
    a2x = MFMA_B16(ah, BL, a2x);                                                \
    a2x = MFMA_B16(al, BH, a2x);                                                \
} while (0)

// full L2 o-tile N2 -> bias+relu+split into HH/HL (s16x4)
#define L2TILE(N2, HH, HL) do {                                                 \
    f32x4 a2h = 0.f, a2x = 0.f;                                                 \
    L2KS(N2, 0, bh1_0, bl1_0);                                                  \
    L2KS(N2, 1, bh1_1, bl1_1);                                                  \
    L2KS(N2, 2, bh1_2, bl1_2);                                                  \
    L2KS(N2, 3, bh1_3, bl1_3);                                                  \
    const int o0 = 16 * (N2) + 4 * l4;                                          \
    f32x4 bb = *(const f32x4*)(sb2 + o0);                                       \
    _Pragma("unroll")                                                           \
    for (int r = 0; r < 4; ++r) {                                               \
        float v = fmaxf(a2h[r] + a2x[r] + bb[r], 0.f);                          \
        short hi, lo; bsplit(v, hi, lo);                                        \
        HH[r] = hi; HL[r] = lo;                                                 \
    }                                                                           \
} while (0)

#define L3KS(N3, KS3, ACC) do {                                                 \
    const s16x8 a3h = *(const s16x8*)(w3h + (((N3) * 4 + (KS3)) * 64 + l) * 8); \
    const s16x8 a3l = *(const s16x8*)(w3l + (((N3) * 4 + (KS3)) * 64 + l) * 8); \
    ACC = MFMA_B16(a3h, b3h, ACC);                                              \
    ACC = MFMA_B16(a3h, b3l, ACC);                                              \
    ACC = MFMA_B16(a3l, b3h, ACC);                                              \
} while (0)

// one h2 k-slice: two L2 o-tiles -> per-wave LDS bounce -> 5 L3 tiles fed
#define KS3_STEP(KS3, N2A, N2B) do {                                            \
    s16x4 hh0 = 0, hl0 = 0, hh1 = 0, hl1 = 0;                                   \
    L2TILE(N2A, hh0, hl0);                                                      \
    if ((N2B) < 7) { L2TILE(N2B, hh1, hl1); }                                   \
    *(s16x4*)(bnH + bnBase + ln * 32 + l4 * 4)      = hh0;                      \
    *(s16x4*)(bnL + bnBase + ln * 32 + l4 * 4)      = hl0;                      \
    *(s16x4*)(bnH + bnBase + ln * 32 + 16 + l4 * 4) = hh1;                      \
    *(s16x4*)(bnL + bnBase + ln * 32 + 16 + l4 * 4) = hl1;                      \
    const s16x8 b3h = *(const s16x8*)(bnH + bnBase + ln * 32 + klo);            \
    const s16x8 b3l = *(const s16x8*)(bnL + bnBase + ln * 32 + klo);            \
    L3KS(0, KS3, acc3_0);                                                       \
    L3KS(1, KS3, acc3_1);                                                       \
    L3KS(2, KS3, acc3_2);                                                       \
    L3KS(3, KS3, acc3_3);                                                       \
    L3KS(4, KS3, acc3_4);                                                       \
} while (0)

#define POOLN(N3, ACC) do {                                                     \
    const int o0 = 16 * (N3) + 4 * l4;                                          \
    f32x4 bb = *(const f32x4*)(sb3 + o0);                                       \
    _Pragma("unroll")                                                           \
    for (int r = 0; r < 4; ++r) {                                               \
        float v = fmaxf(ACC[r] + bb[r], 0.f);                                   \
        v += __shfl_xor(v, 1);                                                  \
        v += __shfl_xor(v, 2);                                                  \
        v += __shfl_xor(v, 4);                                                  \
        v += __shfl_xor(v, 8);                                                  \
        if (ln == 0) pbuf[o0 + r] = v;                                          \
    }                                                                           \
} while (0)

// One batch per block (NO batch loop -> nothing for LICM to hoist -> no spill).
// 2048 blocks x 512 thr; wave w owns el-tile w; 2 blocks/CU co-resident.
__global__ __launch_bounds__(512, 4)
void ds_phi(const float* __restrict__ dyn, const float* __restrict__ stat,
            const float* __restrict__ wsF, const short* __restrict__ wsS,
            const float* __restrict__ rw1, const float* __restrict__ rb1,
            const float* __restrict__ rw2, const float* __restrict__ rb2,
            const float* __restrict__ rw3, const float* __restrict__ rb3,
            const float* __restrict__ qw1, const float* __restrict__ qb1,
            const float* __restrict__ qw2, const float* __restrict__ qb2,
            const float* __restrict__ qw3, const float* __restrict__ qb3,
            float* __restrict__ out) {
    const int tid = threadIdx.x;
    const int w = tid >> 6, l = tid & 63, ln = l & 15, l4 = l >> 4;
    const int klo = l4 * 8;
    const int b = blockIdx.x;

    __shared__ short bnH[4096], bnL[4096];     // per-wave 512-short bounce
    __shared__ float sw1[512], sb2[112], sb3[80];
    __shared__ float poolbuf[8 * 80];
    __shared__ __align__(16) float pooledS[80];
    __shared__ __align__(16) float r1s[64], r2s[64], xcat[48], q1s[200], q2s[104];
    __shared__ float logits[3];

    if (tid < 128) *(f32x4*)(sw1 + tid * 4) = *(const f32x4*)(wsF + W1PK_OFF + tid * 4);
    if (tid < 112) sb2[tid] = wsF[B2PK_OFF + tid];
    if (tid < 80)  sb3[tid] = wsF[B3PK_OFF + tid];
    __syncthreads();

    const short* w2h = wsS + W2H_S;
    const short* w2l = wsS + W2L_S;
    const short* w3h = wsS + W3H_S;
    const short* w3l = wsS + W3L_S;
    const int el = 16 * w + ln;
    const int bnBase = w << 9;
    float* pbuf = poolbuf + w * 80;

    const float* xp = dyn + (size_t)b * 384 + el * 3;
    const float x0 = xp[0], x1 = xp[1], x2 = xp[2];

    // h1 B-frags born in registers (k>=120 rows zero via sw1 padding)
    s16x8 bh1_0, bl1_0, bh1_1, bl1_1, bh1_2, bl1_2, bh1_3, bl1_3;
    #define H1GEN(KS, BH, BL) do {                                          \
        _Pragma("unroll")                                                   \
        for (int j = 0; j < 8; ++j) {                                       \
            const int k = (KS) * 32 + klo + j;                              \
            f32x4 c = *(const f32x4*)(sw1 + 4 * k);                         \
            float v = fmaf(x0, c.x, fmaf(x1, c.y, fmaf(x2, c.z, c.w)));     \
            v = fmaxf(v, 0.f);                                              \
            short hi, lo; bsplit(v, hi, lo);                                \
            BH[j] = hi; BL[j] = lo;                                         \
        }                                                                   \
    } while (0)
    H1GEN(0, bh1_0, bl1_0);
    H1GEN(1, bh1_1, bl1_1);
    H1GEN(2, bh1_2, bl1_2);
    H1GEN(3, bh1_3, bl1_3);
    #undef H1GEN

    f32x4 acc3_0 = 0.f, acc3_1 = 0.f, acc3_2 = 0.f, acc3_3 = 0.f, acc3_4 = 0.f;

    KS3_STEP(0, 0, 1);
    KS3_STEP(1, 2, 3);
    KS3_STEP(2, 4, 5);
    KS3_STEP(3, 6, 7);   // n2=7 stays zero

    POOLN(0, acc3_0);
    POOLN(1, acc3_1);
    POOLN(2, acc3_2);
    POOLN(3, acc3_3);
    POOLN(4, acc3_4);
    __syncthreads();
    if (tid < 80) {
        float s = 0.f;
        #pragma unroll
        for (int ww = 0; ww < 8; ++ww) s += poolbuf[ww * 80 + tid];
        pooledS[tid] = s;
    }
    __syncthreads();

    // ---- fused tail (rho + q + softmax), pooled in LDS ----
    if (tid < 60) {
        float a = rb1[tid];
        for (int k = 0; k < 80; k += 4) {
            f32x4 pv = *(const f32x4*)(pooledS + k);
            f32x4 wv = *(const f32x4*)(rw1 + tid * 80 + k);
            a += pv.x * wv.x + pv.y * wv.y + pv.z * wv.z + pv.w * wv.w;
        }
        r1s[tid] = fmaxf(a, 0.0f);
    }
    __syncthreads();
    if (tid < 60) {
        float a = rb2[tid];
        for (int k = 0; k < 60; k += 4) {
            f32x4 pv = *(const f32x4*)(r1s + k);
            f32x4 wv = *(const f32x4*)(rw2 + tid * 60 + k);
            a += pv.x * wv.x + pv.y * wv.y + pv.z * wv.z + pv.w * wv.w;
        }
        r2s[tid] = fmaxf(a, 0.0f);
    }
    __syncthreads();
    if (tid < 40) {
        float a = rb3[tid];
        for (int k = 0; k < 60; k += 4) {
            f32x4 pv = *(const f32x4*)(r2s + k);
            f32x4 wv = *(const f32x4*)(rw3 + tid * 60 + k);
            a += pv.x * wv.x + pv.y * wv.y + pv.z * wv.z + pv.w * wv.w;
        }
        xcat[tid] = a;
    }
    if (tid >= 40 && tid < 43) xcat[tid] = stat[(size_t)b * 3 + (tid - 40)];
    __syncthreads();
    if (tid < 200) {
        float a = qb1[tid];
        const float* wv = qw1 + tid * 43;
        for (int k = 0; k < 43; ++k) a += xcat[k] * wv[k];
        q1s[tid] = fmaxf(a, 0.0f);
    }
    __syncthreads();
    if (tid < 100) {
        float a = qb2[tid];
        for (int k = 0; k < 200; k += 4) {
            f32x4 pv = *(const f32x4*)(q1s + k);
            f32x4 wv = *(const f32x4*)(qw2 + tid * 200 + k);
            a += pv.x * wv.x + pv.y * wv.y + pv.z * wv.z + pv.w * wv.w;
        }
        q2s[tid] = fmaxf(a, 0.0f);
    }
    __syncthreads();
    if (tid < 96) {
        int o = tid >> 5, l2 = tid & 31;
        float a = 0.0f;
        for (int k = l2; k < 100; k += 32) a += q2s[k] * qw3[o * 100 + k];
        #pragma unroll
        for (int d = 16; d > 0; d >>= 1) a += __shfl_down(a, d, 32);
        if (l2 == 0) logits[o] = a + qb3[o];
    }
    __syncthreads();
    if (tid < 3) {
        float l0 = logits[0], l1 = logits[1], l2v = logits[2];
        float m  = fmaxf(l0, fmaxf(l1, l2v));
        float e0 = __expf(l0 - m), e1 = __expf(l1 - m), e2 = __expf(l2v - m);
        float inv = 1.0f / (e0 + e1 + e2);
        float mine = (tid == 0) ? e0 : ((tid == 1) ? e1 : e2);
        out[(size_t)b * 3 + tid] = mine * inv;
    }
}

extern "C" void kernel_launch(void* const* d_in, const int* in_sizes, int n_in,
                              void* d_out, int out_size, void* d_ws, size_t ws_size,
                              hipStream_t stream) {
    const float* dyn  = (const float*)d_in[0];
    const float* stat = (const float*)d_in[1];
    const float* pw1  = (const float*)d_in[2];
    const float* pb1  = (const float*)d_in[3];
    const float* pw2  = (const float*)d_in[4];
    const float* pb2  = (const float*)d_in[5];
    const float* pw3  = (const float*)d_in[6];
    const float* pb3  = (const float*)d_in[7];
    const float* rw1  = (const float*)d_in[8];
    const float* rb1  = (const float*)d_in[9];
    const float* rw2  = (const float*)d_in[10];
    const float* rb2  = (const float*)d_in[11];
    const float* rw3  = (const float*)d_in[12];
    const float* rb3  = (const float*)d_in[13];
    const float* qw1  = (const float*)d_in[14];
    const float* qb1  = (const float*)d_in[15];
    const float* qw2  = (const float*)d_in[16];
    const float* qb2  = (const float*)d_in[17];
    const float* qw3  = (const float*)d_in[18];
    const float* qb3  = (const float*)d_in[19];
    float* out = (float*)d_out;

    float* wsF = (float*)d_ws;
    short* wsS = (short*)(wsF + WSHORT_OFF);
    const int B = in_sizes[0] / 384;   // 2048

    ds_prep<<<dim3(98), dim3(256), 0, stream>>>(pw1, pb1, pw2, pb2, pw3, pb3, wsF, wsS);
    ds_phi<<<dim3(B), dim3(512), 0, stream>>>(dyn, stat, wsF, wsS,
        rw1, rb1, rw2, rb2, rw3, rb3,
        qw1, qb1, qw2, qb2, qw3, qb3, out);
}